// Round 10
// baseline (628.749 us; speedup 1.0000x reference)
//
#include <hip/hip_runtime.h>
#include <hip/hip_bf16.h>
#include <hip/hip_fp16.h>

// Continuous convolution, single-pass fused design (round 10):
//   r9 shell (VX=4, 512 thr, 38KB LDS, 4 WG/CU, global_load_lds staging) +
//   fp16 feats repack so each edge's row is ONE 64B line (was two).
//   Wall model (r2-r9): random-line service rate of the L2-miss path is
//   ~330GB/s; only fewer lines/bytes helps. Workspace tiers:
//     A: ws >= 17.04MB : wpk + feats_h both in d_ws, one fast kernel.
//     B: ws >= 16MiB   : feats_h in d_ws; wpk in LAST 256KiB of d_out.
//                        Fast kernel = WGs 0..15871 (outputs never touch the
//                        wpk region); slow-W kernel = last 512 WGs, gathers W
//                        from the f32 input and overwrites the scratch tail.
//     C: else          : r9 f32-feats path (wpk in d_ws).
//   Contraction: bf16 hi/lo split MFMA (3 products); B accum f32.

typedef unsigned short u16;
typedef unsigned int   u32;
typedef __attribute__((ext_vector_type(4))) float f32x4;
typedef __attribute__((ext_vector_type(8))) short short8;

#define NOUT    65536
#define VX      4               // voxels per WG
#define THREADS 512
#define EPW     128             // edges per WG
#define NWG     (NOUT / VX)     // 16384
#define NWG_SLOW 512            // tier B: last 512 WGs use slow-W path
#define BSTRIDE 2052            // f32 words per voxel (64 bins * 32 ch + 4 pad)
#define VROWB   (BSTRIDE * 4)   // 8208 bytes
#define BL_BYTES (VX * VROWB)   // 32832 (fstage overlays first part)

// LDS carve (bytes):
#define OFF_W   BL_BYTES              // wls [8][128] f32  (alias Yp 4KB)
#define OFF_BCA (OFF_W + 8*EPW*4)     // bca [128] u32 (bb | mask<<16 | nc<<24)
#define OFF_FB  (OFF_BCA + EPW*4)     // fbase [128] int (feats ROW index)
#define OFF_DEN (OFF_FB + EPW*4)      // den [4] f32
#define SMEM_BYTES (OFF_DEN + 16)     // 37968 -> 4 WG/CU

#define N_IN     262144
#define FH_ELEMS (N_IN * 32)          // 8388608 halves = 16 MiB

// ---- prep: pack W (2048x32 f32) into MFMA B-fragment order, bf16 hi/lo ----
// wpk[tb][bin][lane][j] u16, tb: 0=hi d0-15, 1=lo d0-15, 2=hi d16-31, 3=lo.
// Lane l supplies B[kappa = bin*32 + (l>>4)*8 + j][d = (l&15) + 16*(tb>>1)].
__global__ void prep_w_kernel(const float* __restrict__ W,
                              u16* __restrict__ wpk) {
  int id  = blockIdx.x * 256 + threadIdx.x;   // 0..131071
  int j   = id & 7;
  int l   = (id >> 3) & 63;
  int bin = (id >> 9) & 63;
  int tb  = id >> 15;                         // 0..3
  int kap = (bin << 5) + ((l >> 4) << 3) + j;
  int d   = (l & 15) + ((tb >> 1) << 4);
  float w = W[kap * 32 + d];
  unsigned u = __float_as_uint(w);
  u16 val;
  if (tb & 1) {
    float rem = w - __uint_as_float(u & 0xFFFF0000u);   // exact residual
    val = (u16)(__float_as_uint(rem) >> 16);
  } else {
    val = (u16)(u >> 16);                               // truncated bf16
  }
  wpk[id] = val;
}

// ---- prep: feats f32 -> fp16 (RTNE), 4-wide ----
__global__ void prep_f_kernel(const float* __restrict__ F,
                              __half* __restrict__ Fh) {
  int i = blockIdx.x * 256 + threadIdx.x;     // 0 .. FH_ELEMS/4-1
  f32x4 v = ((const f32x4*)F)[i];
  ushort4 h;
  h.x = __half_as_ushort(__float2half(v[0]));
  h.y = __half_as_ushort(__float2half(v[1]));
  h.z = __half_as_ushort(__float2half(v[2]));
  h.w = __half_as_ushort(__float2half(v[3]));
  ((ushort4*)Fh)[i] = h;
}

template <bool FP16F, bool SLOWW>
__launch_bounds__(THREADS, 8)   // VGPR<=64 so 4 WGs/CU fit wave slots
__global__ void cconv_kernel(const float*  __restrict__ feats,
                             const __half* __restrict__ feats_h,
                             const float*  __restrict__ inp_points,
                             const float*  __restrict__ out_points,
                             const float*  __restrict__ out_extents,
                             const float*  __restrict__ scale_compat,
                             const int*    __restrict__ nbr_idx,
                             const int*    __restrict__ row_splits,
                             const float*  __restrict__ nbr_dist,
                             const float*  __restrict__ bias,
                             const u16*    __restrict__ wpk,
                             const float*  __restrict__ W,
                             float*        __restrict__ out,
                             int wg_base) {
  extern __shared__ __align__(16) char smem[];
  float* wls   = (float*)(smem + OFF_W);
  float* Yp    = wls;                         // alias after scatter done
  u32*   bca   = (u32*)(smem + OFF_BCA);
  int*   fbase = (int*)(smem + OFF_FB);
  float* den   = (float*)(smem + OFF_DEN);

  const int tid  = threadIdx.x;
  const int wg   = wg_base + blockIdx.x;
  const int lane = tid & 63;
  const int wv   = tid >> 6;                  // wave 0..7

  // ---- geometry: one edge per thread (threads 0..127) ----
  if (tid < EPW) {
    const bool is64 = (row_splits[1] == 0);   // int32 view of int64 splits
    int e  = tid;
    int v  = e >> 5;
    int gv = (wg << 2) + v;
    int ge = (wg << 7) + e;
    int idx = nbr_idx[is64 ? (ge << 1) : ge];
    float dist = nbr_dist[ge];
    float sc   = scale_compat[ge];
    float om = 1.f - dist * dist;
    om = fminf(fmaxf(om, 0.f), 1.f);
    float a = sc * om * om * om;
    float inv = 2.f / out_extents[0];
    float ox = out_points[gv * 3 + 0];
    float oy = out_points[gv * 3 + 1];
    float oz = out_points[gv * 3 + 2];
    float rx = (inp_points[idx * 3 + 0] - ox) * inv;
    float ry = (inp_points[idx * 3 + 1] - oy) * inv;
    float rz = (inp_points[idx * 3 + 2] - oz) * inv;
    float n2   = sqrtf(rx * rx + ry * ry + rz * rz + 1e-12f);
    float ninf = fmaxf(fabsf(rx), fmaxf(fabsf(ry), fabsf(rz)));
    float scl  = (ninf > 1e-8f) ? (n2 / ninf) : 0.f;
    float cx = fminf(fmaxf(rx * scl, -1.f), 1.f);
    float cy = fminf(fmaxf(ry * scl, -1.f), 1.f);
    float cz = fminf(fmaxf(rz * scl, -1.f), 1.f);
    float ux = fminf(fmaxf((cx + 1.f) * 1.5f, 0.f), 3.f);
    float uy = fminf(fmaxf((cy + 1.f) * 1.5f, 0.f), 3.f);
    float uz = fminf(fmaxf((cz + 1.f) * 1.5f, 0.f), 3.f);
    float fx = fminf(floorf(ux), 2.f);
    float fy = fminf(floorf(uy), 2.f);
    float fz = fminf(floorf(uz), 2.f);
    float tx = ux - fx, ty = uy - fy, tz = uz - fz;
    int ix = (int)fx, iy = (int)fy, iz = (int)fz;
    float X1 = tx * a, X0 = a - X1;           // fold importance into x weights
    float Y1 = ty,     Y0 = 1.f - ty;
    float Z1 = tz,     Z0 = 1.f - tz;
    float p00 = X0 * Y0, p01 = X0 * Y1, p10 = X1 * Y0, p11 = X1 * Y1;
    float wc[8];
    wc[0] = p00 * Z0; wc[1] = p00 * Z1; wc[2] = p01 * Z0; wc[3] = p01 * Z1;
    wc[4] = p10 * Z0; wc[5] = p10 * Z1; wc[6] = p11 * Z0; wc[7] = p11 * Z1;
    int kb = (ix * 4 + iy) * 4 + iz;          // base bin (<=42)
    u32 bb = (u32)(v * VROWB + (kb << 7));    // < 32768
    int nc = 0; u32 mask = 0;
    #pragma unroll
    for (int k = 0; k < 8; ++k) {
      if (wc[k] != 0.f) {
        wls[nc * EPW + e] = wc[k];
        mask |= (1u << k);
        ++nc;
      }
    }
    bca[e]   = bb | (mask << 16) | ((u32)nc << 24);
    fbase[e] = idx;                           // feats ROW index
    // per-voxel denom: half-wave (32 lanes = 1 voxel) shuffle reduction
    float s = a;
    s += __shfl_xor(s, 1);
    s += __shfl_xor(s, 2);
    s += __shfl_xor(s, 4);
    s += __shfl_xor(s, 8);
    s += __shfl_xor(s, 16);
    if ((lane & 31) == 0) den[v] = s;
  }
  __syncthreads();

  // ---- stage all 128 feats rows into LDS (overlaying B region) ----
  if (FP16F) {
    // fp16 rows: 64B each; chunk t (0..511): row r=t>>2, 16B piece k=t&3.
    int r = tid >> 2;
    int k = tid & 3;
    const __half* g = feats_h + ((size_t)fbase[r] << 5) + (k << 3);
    __builtin_amdgcn_global_load_lds(
        (const __attribute__((address_space(1))) void*)(const void*)g,
        (__attribute__((address_space(3))) void*)(void*)(smem + (tid << 4)),
        16, 0, 0);
  } else {
    // f32 rows: 128B each; 1024 chunks in 2 rounds.
    #pragma unroll
    for (int rd = 0; rd < 2; ++rd) {
      int t = (rd << 9) + tid;
      int r = t >> 3;
      int k = t & 7;
      const float* g = feats + ((size_t)fbase[r] << 5) + (k << 2);
      __builtin_amdgcn_global_load_lds(
          (const __attribute__((address_space(1))) void*)(const void*)g,
          (__attribute__((address_space(3))) void*)(void*)(smem + (t << 4)),
          16, 0, 0);
    }
  }
  __syncthreads();   // drains vmcnt: stage complete

  // ---- pull this thread's 8 feats values LDS -> regs ----
  const int c  = tid & 31;                    // channel
  const int e0 = tid >> 5;                    // 0..15
  float fg[8];
  if (FP16F) {
    const __half* fs = (const __half*)smem;
    #pragma unroll
    for (int it = 0; it < 8; ++it)
      fg[it] = __half2float(fs[(((it << 4) + e0) << 5) + c]);
  } else {
    const float* fs = (const float*)smem;
    #pragma unroll
    for (int it = 0; it < 8; ++it)
      fg[it] = fs[(((it << 4) + e0) << 5) + c];
  }
  __syncthreads();   // everyone done reading fstage

  // ---- zero B tile (all threads) ----
  {
    f32x4 z = {0.f, 0.f, 0.f, 0.f};
    for (int i = tid; i < (BL_BYTES / 16); i += THREADS)
      ((f32x4*)smem)[i] = z;
  }
  __syncthreads();

  // ---- scatter: lane=channel, half-wave=edge row ----
  {
    #pragma unroll
    for (int it = 0; it < 8; ++it) {
      int   e    = (it << 4) + e0;
      u32   m    = bca[e];
      u32   base = (m & 0xFFFFu) + ((u32)c << 2);
      u32   mask = (m >> 16) & 0xFFu;
      int   nc   = (int)(m >> 24);
      float f    = fg[it];
      for (int j = 0; j < nc; ++j) {          // ~2-3 iters, uniform per edge
        float w = wls[j * EPW + e];           // broadcast within half-wave
        int   k = __builtin_ctz(mask);
        mask &= mask - 1;
        u32 d = ((k & 1) << 7) | ((k & 2) << 8) | ((k & 4) << 9);
        atomicAdd((float*)(smem + base + d), w * f);  // banks 0..31, <=2-way
      }
    }
  }
  __syncthreads();

  // ---- MFMA contraction: wave wv owns bins [8*wv, 8*wv+8) ----
  f32x4 acc0 = {0.f, 0.f, 0.f, 0.f};          // cout 0..15
  f32x4 acc1 = {0.f, 0.f, 0.f, 0.f};          // cout 16..31
  {
    const short8* wp = (const short8*)wpk;    // [4][64][64] fragments
    int v16 = lane & 15;                      // A row (rows 4-15 dup of 0-3)
    int q   = lane >> 4;
    const char* arow = smem + (size_t)(v16 & 3) * VROWB;
    #pragma unroll
    for (int b = 0; b < 8; ++b) {
      int bin = (wv << 3) + b;
      short8 w0h, w0l, w1h, w1l;
      if (!SLOWW) {
        // coalesced 1KB-burst B-fragment loads (L2-resident)
        w0h = wp[((0 * 64 + bin) << 6) + lane];
        w0l = wp[((1 * 64 + bin) << 6) + lane];
        w1h = wp[((2 * 64 + bin) << 6) + lane];
        w1l = wp[((3 * 64 + bin) << 6) + lane];
      } else {
        // gather from f32 W and split hi/lo inline (only 512 WGs take this)
        #pragma unroll
        for (int j = 0; j < 8; ++j) {
          int kap = (bin << 5) + (q << 3) + j;
          float f0 = W[kap * 32 + v16];
          float f1 = W[kap * 32 + v16 + 16];
          unsigned u0 = __float_as_uint(f0);
          w0h[j] = (short)(u0 >> 16);
          float r0 = f0 - __uint_as_float(u0 & 0xFFFF0000u);
          w0l[j] = (short)(__float_as_uint(r0) >> 16);
          unsigned u1 = __float_as_uint(f1);
          w1h[j] = (short)(u1 >> 16);
          float r1 = f1 - __uint_as_float(u1 & 0xFFFF0000u);
          w1l[j] = (short)(__float_as_uint(r1) >> 16);
        }
      }
      const float* ap = (const float*)(arow + (bin << 7) + (q << 5));
      f32x4 a0 = *(const f32x4*)ap;           // ch k0..k0+3
      f32x4 a1 = *(const f32x4*)(ap + 4);     // ch k0+4..k0+7
      short8 ahi, alo;
      #pragma unroll
      for (int j = 0; j < 4; ++j) {
        unsigned u0 = __float_as_uint(a0[j]);
        ahi[j] = (short)(u0 >> 16);
        float r0 = a0[j] - __uint_as_float(u0 & 0xFFFF0000u);
        alo[j] = (short)(__float_as_uint(r0) >> 16);
        unsigned u1 = __float_as_uint(a1[j]);
        ahi[j + 4] = (short)(u1 >> 16);
        float r1 = a1[j] - __uint_as_float(u1 & 0xFFFF0000u);
        alo[j + 4] = (short)(__float_as_uint(r1) >> 16);
      }
      acc0 = __builtin_amdgcn_mfma_f32_16x16x32_bf16(ahi, w0h, acc0, 0, 0, 0);
      acc0 = __builtin_amdgcn_mfma_f32_16x16x32_bf16(ahi, w0l, acc0, 0, 0, 0);
      acc0 = __builtin_amdgcn_mfma_f32_16x16x32_bf16(alo, w0h, acc0, 0, 0, 0);
      acc1 = __builtin_amdgcn_mfma_f32_16x16x32_bf16(ahi, w1h, acc1, 0, 0, 0);
      acc1 = __builtin_amdgcn_mfma_f32_16x16x32_bf16(ahi, w1l, acc1, 0, 0, 0);
      acc1 = __builtin_amdgcn_mfma_f32_16x16x32_bf16(alo, w1h, acc1, 0, 0, 0);
    }
  }

  // ---- per-wave partials: valid C rows 0..3 live in lanes 0..15, regs 0..3
  // C/D layout: col = lane&15 (cout), row = (lane>>4)*4 + reg (voxel)
  if (lane < 16) {
    float* yp = Yp + (wv << 7);               // 4 v x 32 d per wave
    #pragma unroll
    for (int r = 0; r < 4; ++r) {
      yp[r * 32 + lane]      = acc0[r];
      yp[r * 32 + 16 + lane] = acc1[r];
    }
  }
  __syncthreads();

  // ---- reduce 8 wave-partials, normalize, bias, relu, store ----
  if (tid < EPW) {
    float s = 0.f;
    #pragma unroll
    for (int w = 0; w < 8; ++w) s += Yp[(w << 7) + tid];
    int v = tid >> 5;
    int d = tid & 31;
    float dn = fmaxf(den[v], 1e-8f);
    float y = s / dn + bias[d];
    out[(wg << 7) + tid] = fmaxf(y, 0.f);
  }
}

extern "C" void kernel_launch(void* const* d_in, const int* in_sizes, int n_in,
                              void* d_out, int out_size, void* d_ws, size_t ws_size,
                              hipStream_t stream) {
  const float* feats        = (const float*)d_in[0];
  const float* inp_points   = (const float*)d_in[1];
  const float* out_points   = (const float*)d_in[2];
  const float* out_extents  = (const float*)d_in[3];
  const float* scale_compat = (const float*)d_in[4];
  const int*   nbr_idx      = (const int*)d_in[5];
  const int*   row_splits   = (const int*)d_in[6];
  const float* nbr_dist     = (const float*)d_in[7];
  const float* W            = (const float*)d_in[8];
  const float* bias         = (const float*)d_in[9];
  float*       outp         = (float*)d_out;

  const size_t FH_BYTES  = (size_t)FH_ELEMS * 2;     // 16 MiB
  const size_t WPK_BYTES = 262144;                   // 256 KiB

  (void)hipFuncSetAttribute((const void*)cconv_kernel<true, false>,
                            hipFuncAttributeMaxDynamicSharedMemorySize, SMEM_BYTES);
  (void)hipFuncSetAttribute((const void*)cconv_kernel<true, true>,
                            hipFuncAttributeMaxDynamicSharedMemorySize, SMEM_BYTES);
  (void)hipFuncSetAttribute((const void*)cconv_kernel<false, false>,
                            hipFuncAttributeMaxDynamicSharedMemorySize, SMEM_BYTES);

  if (ws_size >= FH_BYTES + WPK_BYTES) {
    // Tier A: everything in d_ws
    __half* feats_h = (__half*)d_ws;
    u16*    wpk     = (u16*)((char*)d_ws + FH_BYTES);
    prep_f_kernel<<<FH_ELEMS / 4 / 256, 256, 0, stream>>>(feats, feats_h);
    prep_w_kernel<<<512, 256, 0, stream>>>(W, wpk);
    cconv_kernel<true, false><<<NWG, THREADS, SMEM_BYTES, stream>>>(
        feats, feats_h, inp_points, out_points, out_extents, scale_compat,
        nbr_idx, row_splits, nbr_dist, bias, wpk, W, outp, 0);
  } else if (ws_size >= FH_BYTES) {
    // Tier B: feats_h fills d_ws; wpk borrows the LAST 256KiB of d_out.
    // Fast kernel covers WGs 0..NWG-513 (outputs end before the wpk region);
    // slow-W kernel covers the last 512 WGs afterwards and overwrites it.
    __half* feats_h = (__half*)d_ws;
    u16*    wpk     = (u16*)((char*)d_out + (size_t)out_size * 4 - WPK_BYTES);
    prep_f_kernel<<<FH_ELEMS / 4 / 256, 256, 0, stream>>>(feats, feats_h);
    prep_w_kernel<<<512, 256, 0, stream>>>(W, wpk);
    cconv_kernel<true, false><<<NWG - NWG_SLOW, THREADS, SMEM_BYTES, stream>>>(
        feats, feats_h, inp_points, out_points, out_extents, scale_compat,
        nbr_idx, row_splits, nbr_dist, bias, wpk, W, outp, 0);
    cconv_kernel<true, true><<<NWG_SLOW, THREADS, SMEM_BYTES, stream>>>(
        feats, feats_h, inp_points, out_points, out_extents, scale_compat,
        nbr_idx, row_splits, nbr_dist, bias, (const u16*)nullptr, W, outp,
        NWG - NWG_SLOW);
  } else {
    // Tier C: f32 feats (r9 path), wpk in d_ws
    u16* wpk = (u16*)d_ws;
    prep_w_kernel<<<512, 256, 0, stream>>>(W, wpk);
    cconv_kernel<false, false><<<NWG, THREADS, SMEM_BYTES, stream>>>(
        feats, (const __half*)nullptr, inp_points, out_points, out_extents,
        scale_compat, nbr_idx, row_splits, nbr_dist, bias, wpk, W, outp, 0);
  }
}